// Round 10
// baseline (626.824 us; speedup 1.0000x reference)
//
#include <hip/hip_runtime.h>
#include <stdint.h>

#define RESO 192
#define NVOX (RESO * RESO * RESO)
#define DATA_DIM 28
#define CHUNKS 7        // DATA_DIM / 4
#define TPA 24          // bins per axis (bin = 8 cells)
#define NBIN 13824      // TPA^3
#define NXCD 8
#define BPX 1728        // bins per XCD (x-slab of 3)
#define BLOCKS_P 256    // histogram / scatter blocks
#define ROWF 252        // 9 z-nodes * 28 floats per (x,y) LDS row
#define STAGE_F (81 * ROWF)          // 20412 floats = 79.7 KB
#define STAGE_LD (81 * (ROWF / 4))   // 5103 float4 loads

// ---------------- shared device helpers ----------------

__device__ __forceinline__ float4 f4_lerp(float4 a, float4 b, float wa, float wb) {
    float4 r;
    r.x = fmaf(a.x, wa, b.x * wb);
    r.y = fmaf(a.y, wa, b.y * wb);
    r.z = fmaf(a.z, wa, b.z * wb);
    r.w = fmaf(a.w, wa, b.w * wb);
    return r;
}

__device__ __forceinline__ int point_coords(
    const float* __restrict__ points,
    const float* __restrict__ offset,
    const float* __restrict__ scaling,
    int p, int* l, float* wb)
{
    int t = 0;
#pragma unroll
    for (int i = 0; i < 3; ++i) {
        float v = fmaf(points[(size_t)p * 3 + i], scaling[i] * (float)RESO,
                       offset[i] * (float)RESO - 0.5f);
        v = fminf(fmaxf(v, 0.0f), (float)RESO - 1.0f);
        int li = (int)v;                 // v >= 0 -> trunc == floor
        if (li > RESO - 2) li = RESO - 2;
        l[i] = li;
        wb[i] = v - (float)li;
        t = t * TPA + (li >> 3);         // bin = 8 cells
    }
    return t;
}

__device__ __forceinline__ float4 trilerp8(const float4* cv, float4 pw) {
    const float waz = 1.0f - pw.z, wbz = pw.z;
    const float way = 1.0f - pw.y, wby = pw.y;
    const float wax = 1.0f - pw.x, wbx = pw.x;
    float4 c00 = f4_lerp(cv[0], cv[1], waz, wbz);
    float4 c01 = f4_lerp(cv[2], cv[3], waz, wbz);
    float4 c10 = f4_lerp(cv[4], cv[5], waz, wbz);
    float4 c11 = f4_lerp(cv[6], cv[7], waz, wbz);
    float4 c0 = f4_lerp(c00, c01, way, wby);
    float4 c1 = f4_lerp(c10, c11, way, wby);
    return f4_lerp(c0, c1, wax, wbx);
}

// ---------------- links == arange detector ----------------

__global__ void k_init_flag(int* __restrict__ flag) {
    if (threadIdx.x == 0) flag[0] = 1;
}

__global__ __launch_bounds__(256) void k_check_links(
    const int* __restrict__ links, int* __restrict__ flag)
{
    bool ok = true;
    for (int i = blockIdx.x * 256 + threadIdx.x; i < NVOX; i += gridDim.x * 256)
        ok &= (links[i] == i);
    if (!ok) atomicAnd(flag, 0);   // never executes for identity links
}

// ---------------- sort pipeline (global-atomic-free) ----------------
// ghist/goff layout: [BLOCKS_P][NBIN]  (coalesced for every accessor)

__global__ __launch_bounds__(256) void k_hist(
    const float* __restrict__ points,
    const float* __restrict__ offset,
    const float* __restrict__ scaling,
    int* __restrict__ ghist,
    int n, int ppb)
{
    __shared__ int lh[NBIN];   // 54 KB
    for (int i = threadIdx.x; i < NBIN; i += 256) lh[i] = 0;
    __syncthreads();
    const int b = blockIdx.x;
    const int lo = b * ppb;
    const int hi = min(lo + ppb, n);
    for (int p = lo + threadIdx.x; p < hi; p += 256) {
        int l[3]; float wb[3];
        const int t = point_coords(points, offset, scaling, p, l, wb);
        atomicAdd(&lh[t], 1);
    }
    __syncthreads();
    int* orow = ghist + (size_t)b * NBIN;
    for (int i = threadIdx.x; i < NBIN; i += 256) orow[i] = lh[i];
}

// thread-per-bin column sum (reads coalesced across bins)
__global__ __launch_bounds__(256) void k_rowsum(
    const int* __restrict__ ghist, int* __restrict__ binsum)
{
    const int bin = blockIdx.x * 256 + threadIdx.x;
    if (bin >= NBIN) return;
    int s = 0;
    for (int b = 0; b < BLOCKS_P; ++b) s += ghist[(size_t)b * NBIN + bin];
    binsum[bin] = s;
}

__global__ __launch_bounds__(512) void k_scan_bins(
    const int* __restrict__ binsum, int* __restrict__ csum)
{
    __shared__ int vals[NBIN];   // 54 KB
    __shared__ int part[512];
    const int t = threadIdx.x;
    const int PER = NBIN / 512;  // 27
    int s = 0;
    for (int i = 0; i < PER; ++i) { int v = binsum[t * PER + i]; vals[t * PER + i] = v; s += v; }
    part[t] = s;
    __syncthreads();
    for (int d = 1; d < 512; d <<= 1) {
        int v = part[t];
        int add = (t >= d) ? part[t - d] : 0;
        __syncthreads();
        part[t] = v + add;
        __syncthreads();
    }
    int run = (t == 0) ? 0 : part[t - 1];
    for (int i = 0; i < PER; ++i) { int v = vals[t * PER + i]; csum[t * PER + i] = run; run += v; }
    if (t == 511) csum[NBIN] = run;
}

// thread-per-bin serial scan over blocks (coalesced in bin)
__global__ __launch_bounds__(256) void k_scan_blocks(
    const int* __restrict__ ghist,
    const int* __restrict__ csum,
    int* __restrict__ goff)
{
    const int bin = blockIdx.x * 256 + threadIdx.x;
    if (bin >= NBIN) return;
    int run = csum[bin];
    for (int b = 0; b < BLOCKS_P; ++b) {
        goff[(size_t)b * NBIN + bin] = run;
        run += ghist[(size_t)b * NBIN + bin];
    }
}

// scatter: perm + packed payload {wb0,wb1,wb2, (lx<<16|ly<<8|lz)}
__global__ __launch_bounds__(256) void k_scatter(
    const float* __restrict__ points,
    const float* __restrict__ offset,
    const float* __restrict__ scaling,
    const int* __restrict__ goff,
    int* __restrict__ perm,
    float4* __restrict__ pre4,
    int n, int ppb)
{
    __shared__ int cur[NBIN];   // 54 KB
    const int b = blockIdx.x;
    const int* grow = goff + (size_t)b * NBIN;
    for (int i = threadIdx.x; i < NBIN; i += 256) cur[i] = grow[i];
    __syncthreads();
    const int lo = b * ppb;
    const int hi = min(lo + ppb, n);
    for (int p = lo + threadIdx.x; p < hi; p += 256) {
        int l[3]; float wb[3];
        const int t = point_coords(points, offset, scaling, p, l, wb);
        const int slot = atomicAdd(&cur[t], 1);   // LDS atomic only
        const unsigned lpack = ((unsigned)l[0] << 16) | ((unsigned)l[1] << 8) | (unsigned)l[2];
        perm[slot] = p;
        pre4[slot] = make_float4(wb[0], wb[1], wb[2], __uint_as_float(lpack));
    }
}

// ---------------- main sampler: LDS-tiled (zero scattered global gathers) ----------------

__global__ __launch_bounds__(256) void k_sample_tiled(
    const int*    __restrict__ perm,
    const float4* __restrict__ pre4,
    const int*    __restrict__ csum,
    const float*  __restrict__ data,
    const int*    __restrict__ links,
    const int*    __restrict__ flag,
    float*        __restrict__ out)
{
    extern __shared__ float lds[];   // STAGE_F floats = 79.7 KB -> 2 blocks/CU

    const int k   = blockIdx.x & (NXCD - 1);   // XCD id (round-robin dispatch)
    const int j   = blockIdx.x >> 3;           // bin within XCD slab
    const int bin = k * BPX + j;
    const int bx = bin / (TPA * TPA);
    const int by = (bin / TPA) % TPA;
    const int bz = bin % TPA;
    const int b0x = min(bx * 8, RESO - 9);     // staged node window [b0,b0+8]
    const int b0y = min(by * 8, RESO - 9);
    const int b0z = min(bz * 8, RESO - 9);

    const bool fast = (flag[0] != 0);          // block-uniform
    const int lo = csum[bin], hi = csum[bin + 1];
    const int items = (hi - lo) * CHUNKS;

    if (fast) {
        // stage 9x9 (x,y) rows, each 9 z-nodes * 28 floats = 252 contiguous floats
        for (int i = threadIdx.x; i < STAGE_LD; i += 256) {
            const int pair = i / 63;
            const int f4   = i - pair * 63;
            const int gx = b0x + pair / 9;
            const int gy = b0y + (pair - (pair / 9) * 9);
            const float* src = data + ((size_t)(gx * RESO + gy) * RESO + b0z) * DATA_DIM
                             + (size_t)f4 * 4;
            *reinterpret_cast<float4*>(lds + pair * ROWF + f4 * 4) =
                *reinterpret_cast<const float4*>(src);
        }
    }
    __syncthreads();

    const int dzf = 28, dyf = ROWF, dxf = 9 * ROWF;   // LDS float strides
    const int dz = 1, dy = RESO, dx = RESO * RESO;    // global strides

    for (int i = threadIdx.x; i < items; i += 256) {
        const int slot = lo + i / CHUNKS;
        const int c    = i - (i / CHUNKS) * CHUNKS;
        const int p    = perm[slot];          // broadcast across 7 chunk-lanes
        const float4 pw = pre4[slot];         // broadcast
        const unsigned lp = __float_as_uint(pw.w);
        const int lx = lp >> 16, ly = (lp >> 8) & 255, lz = lp & 255;

        float4 cv[8];
        if (fast) {
            const float* fb = lds + ((lx - b0x) * 9 + (ly - b0y)) * ROWF
                            + (lz - b0z) * 28 + c * 4;
            cv[0] = *reinterpret_cast<const float4*>(fb);
            cv[1] = *reinterpret_cast<const float4*>(fb + dzf);
            cv[2] = *reinterpret_cast<const float4*>(fb + dyf);
            cv[3] = *reinterpret_cast<const float4*>(fb + dyf + dzf);
            cv[4] = *reinterpret_cast<const float4*>(fb + dxf);
            cv[5] = *reinterpret_cast<const float4*>(fb + dxf + dzf);
            cv[6] = *reinterpret_cast<const float4*>(fb + dxf + dyf);
            cv[7] = *reinterpret_cast<const float4*>(fb + dxf + dyf + dzf);
        } else {
            const int gbase = (lx * RESO + ly) * RESO + lz;
            const int offs[8] = {0, dz, dy, dy + dz, dx, dx + dz, dx + dy, dx + dy + dz};
            int lk[8];
#pragma unroll
            for (int q = 0; q < 8; ++q) lk[q] = links[gbase + offs[q]];
#pragma unroll
            for (int q = 0; q < 8; ++q)
                cv[q] = *reinterpret_cast<const float4*>(
                    data + (size_t)(lk[q] < 0 ? 0 : lk[q]) * DATA_DIM + (size_t)c * 4);
#pragma unroll
            for (int q = 0; q < 8; ++q)
                if (lk[q] < 0) cv[q] = make_float4(0.f, 0.f, 0.f, 0.f);
        }

        const float4 s = trilerp8(cv, pw);
        *reinterpret_cast<float4*>(out + (size_t)p * DATA_DIM + (size_t)c * 4) = s;
    }
}

// ---------------- fallback: direct order ----------------

__global__ __launch_bounds__(256) void k_sample_direct(
    const float* __restrict__ points,
    const float* __restrict__ data,
    const int*   __restrict__ links,
    const float* __restrict__ offset,
    const float* __restrict__ scaling,
    float*       __restrict__ out,
    int n_pts)
{
    const int tid = blockIdx.x * blockDim.x + threadIdx.x;
    const int total = n_pts * CHUNKS;
    if (tid >= total) return;
    const int p = tid / CHUNKS;
    const int c = tid - p * CHUNKS;

    int l[3]; float wb[3];
    (void)point_coords(points, offset, scaling, p, l, wb);
    const int gbase = (l[0] * RESO + l[1]) * RESO + l[2];

    const int dz = 1, dy = RESO, dx = RESO * RESO;
    int lk[8];
    lk[0] = links[gbase];
    lk[1] = links[gbase + dz];
    lk[2] = links[gbase + dy];
    lk[3] = links[gbase + dy + dz];
    lk[4] = links[gbase + dx];
    lk[5] = links[gbase + dx + dz];
    lk[6] = links[gbase + dx + dy];
    lk[7] = links[gbase + dx + dy + dz];

    float4 cv[8];
#pragma unroll
    for (int q = 0; q < 8; ++q) {
        const int idx = lk[q] < 0 ? 0 : lk[q];
        cv[q] = *reinterpret_cast<const float4*>(
            data + (size_t)idx * DATA_DIM + (size_t)c * 4);
    }
#pragma unroll
    for (int q = 0; q < 8; ++q)
        if (lk[q] < 0) cv[q] = make_float4(0.f, 0.f, 0.f, 0.f);

    float4 pw = make_float4(wb[0], wb[1], wb[2], 0.f);
    const float4 s = trilerp8(cv, pw);
    *reinterpret_cast<float4*>(out + (size_t)tid * 4) = s;
}

// ---------------- launch ----------------

extern "C" void kernel_launch(void* const* d_in, const int* in_sizes, int n_in,
                              void* d_out, int out_size, void* d_ws, size_t ws_size,
                              hipStream_t stream)
{
    const float* points  = (const float*)d_in[0];
    const float* data    = (const float*)d_in[1];
    const int*   links   = (const int*)d_in[2];
    const float* offset  = (const float*)d_in[3];
    const float* scaling = (const float*)d_in[4];
    float*       out     = (float*)d_out;

    const int n_pts = in_sizes[0] / 3;

    // ws layout: flag | ghist | goff | binsum | csum | perm | pre4
    size_t off = 0;
    auto alloc = [&](size_t bytes) {
        size_t a = off;
        off = (off + bytes + 255) & ~(size_t)255;
        return a;
    };
    const size_t o_flag   = alloc(4);
    const size_t o_ghist  = alloc((size_t)NBIN * BLOCKS_P * 4);
    const size_t o_goff   = alloc((size_t)NBIN * BLOCKS_P * 4);
    const size_t o_binsum = alloc((size_t)NBIN * 4);
    const size_t o_csum   = alloc((size_t)(NBIN + 1) * 4);
    const size_t o_perm   = alloc((size_t)n_pts * 4);
    const size_t o_pre4   = alloc((size_t)n_pts * 16);
    const size_t need = off;

    if (ws_size >= need) {
        int*    flag   = (int*)((char*)d_ws + o_flag);
        int*    ghist  = (int*)((char*)d_ws + o_ghist);
        int*    goff   = (int*)((char*)d_ws + o_goff);
        int*    binsum = (int*)((char*)d_ws + o_binsum);
        int*    csum   = (int*)((char*)d_ws + o_csum);
        int*    perm   = (int*)((char*)d_ws + o_perm);
        float4* pre4   = (float4*)((char*)d_ws + o_pre4);

        const int ppb = (n_pts + BLOCKS_P - 1) / BLOCKS_P;

        k_init_flag<<<1, 64, 0, stream>>>(flag);
        k_check_links<<<2048, 256, 0, stream>>>(links, flag);
        k_hist<<<BLOCKS_P, 256, 0, stream>>>(points, offset, scaling, ghist, n_pts, ppb);
        k_rowsum<<<(NBIN + 255) / 256, 256, 0, stream>>>(ghist, binsum);
        k_scan_bins<<<1, 512, 0, stream>>>(binsum, csum);
        k_scan_blocks<<<(NBIN + 255) / 256, 256, 0, stream>>>(ghist, csum, goff);
        k_scatter<<<BLOCKS_P, 256, 0, stream>>>(points, offset, scaling, goff,
                                                perm, pre4, n_pts, ppb);

        k_sample_tiled<<<NBIN, 256, STAGE_F * 4, stream>>>(
            perm, pre4, csum, data, links, flag, out);
    } else {
        const int total = n_pts * CHUNKS;
        k_sample_direct<<<(total + 255) / 256, 256, 0, stream>>>(
            points, data, links, offset, scaling, out, n_pts);
    }
}

// Round 11
// 418.224 us; speedup vs baseline: 1.4988x; 1.4988x over previous
//
#include <hip/hip_runtime.h>
#include <stdint.h>

#define RESO 192
#define NVOX (RESO * RESO * RESO)
#define DATA_DIM 28
#define CHUNKS 7        // DATA_DIM / 4
#define TPA 12          // tiles per axis (tile = 16 cells)
#define NT 1728         // TPA^3 bins
#define NXCD 8
#define TPX 216         // NT / NXCD -> contiguous x-slab per XCD
#define BLOCKS_P 256    // histogram / scatter blocks

// ---------------- shared device helpers ----------------

__device__ __forceinline__ float4 f4_lerp(float4 a, float4 b, float wa, float wb) {
    float4 r;
    r.x = fmaf(a.x, wa, b.x * wb);
    r.y = fmaf(a.y, wa, b.y * wb);
    r.z = fmaf(a.z, wa, b.z * wb);
    r.w = fmaf(a.w, wa, b.w * wb);
    return r;
}

__device__ __forceinline__ int point_coords(
    const float* __restrict__ points,
    const float* __restrict__ offset,
    const float* __restrict__ scaling,
    int p, int* l, float* wb)
{
    int t = 0;
#pragma unroll
    for (int i = 0; i < 3; ++i) {
        float v = fmaf(points[(size_t)p * 3 + i], scaling[i] * (float)RESO,
                       offset[i] * (float)RESO - 0.5f);
        v = fminf(fmaxf(v, 0.0f), (float)RESO - 1.0f);
        int li = (int)v;                 // v >= 0 -> trunc == floor
        if (li > RESO - 2) li = RESO - 2;
        l[i] = li;
        wb[i] = v - (float)li;
        t = t * TPA + (li >> 4);         // tile = 16 cells
    }
    return t;
}

__device__ __forceinline__ float4 trilerp8(const float4* cv, float wx, float wy, float wz) {
    const float waz = 1.0f - wz, wbz = wz;
    const float way = 1.0f - wy, wby = wy;
    const float wax = 1.0f - wx, wbx = wx;
    float4 c00 = f4_lerp(cv[0], cv[1], waz, wbz);
    float4 c01 = f4_lerp(cv[2], cv[3], waz, wbz);
    float4 c10 = f4_lerp(cv[4], cv[5], waz, wbz);
    float4 c11 = f4_lerp(cv[6], cv[7], waz, wbz);
    float4 c0 = f4_lerp(c00, c01, way, wby);
    float4 c1 = f4_lerp(c10, c11, way, wby);
    return f4_lerp(c0, c1, wax, wbx);
}

// ---------------- links == arange detector ----------------

__global__ void k_init_flag(int* __restrict__ flag) {
    if (threadIdx.x == 0) flag[0] = 1;
}

__global__ __launch_bounds__(256) void k_check_links(
    const int* __restrict__ links, int* __restrict__ flag)
{
    bool ok = true;
    for (int i = blockIdx.x * 256 + threadIdx.x; i < NVOX; i += gridDim.x * 256)
        ok &= (links[i] == i);
    if (!ok) atomicAnd(flag, 0);   // never executes for identity links
}

// ---------------- sort pipeline (global-atomic-free) ----------------

__global__ __launch_bounds__(256) void k_hist(
    const float* __restrict__ points,
    const float* __restrict__ offset,
    const float* __restrict__ scaling,
    int* __restrict__ ghist,   // [NT][BLOCKS_P]
    int n, int ppb)
{
    __shared__ int lh[NT];
    for (int i = threadIdx.x; i < NT; i += 256) lh[i] = 0;
    __syncthreads();
    const int b = blockIdx.x;
    const int lo = b * ppb;
    const int hi = min(lo + ppb, n);
    for (int p = lo + threadIdx.x; p < hi; p += 256) {
        int l[3]; float wb[3];
        const int t = point_coords(points, offset, scaling, p, l, wb);
        atomicAdd(&lh[t], 1);
    }
    __syncthreads();
    for (int i = threadIdx.x; i < NT; i += 256)
        ghist[(size_t)i * BLOCKS_P + b] = lh[i];
}

__global__ __launch_bounds__(256) void k_rowsum(
    const int* __restrict__ ghist, int* __restrict__ binsum)
{
    const int wave = (blockIdx.x * 256 + threadIdx.x) >> 6;
    const int lane = threadIdx.x & 63;
    if (wave >= NT) return;
    const int* row = ghist + (size_t)wave * BLOCKS_P;
    int s = 0;
#pragma unroll
    for (int i = 0; i < BLOCKS_P / 64; ++i) s += row[lane + i * 64];
#pragma unroll
    for (int d = 32; d > 0; d >>= 1) s += __shfl_xor(s, d, 64);
    if (lane == 0) binsum[wave] = s;
}

__global__ __launch_bounds__(1024) void k_scan_bins(
    const int* __restrict__ binsum, int* __restrict__ csum)
{
    __shared__ int buf[2][2048];
    for (int t = threadIdx.x; t < 2048; t += 1024)
        buf[0][t] = (t < NT) ? binsum[t] : 0;
    __syncthreads();
    int src = 0;
    for (int d = 1; d < 2048; d <<= 1) {
        for (int t = threadIdx.x; t < 2048; t += 1024)
            buf[src ^ 1][t] = buf[src][t] + (t >= d ? buf[src][t - d] : 0);
        __syncthreads();
        src ^= 1;
    }
    for (int t = threadIdx.x; t < NT; t += 1024)
        csum[t] = t ? buf[src][t - 1] : 0;
    if (threadIdx.x == 0) csum[NT] = buf[src][NT - 1];
}

__global__ __launch_bounds__(256) void k_scan_blocks(
    const int* __restrict__ ghist,
    const int* __restrict__ csum,
    int* __restrict__ goff)
{
    const int wave = (blockIdx.x * 256 + threadIdx.x) >> 6;
    const int lane = threadIdx.x & 63;
    if (wave >= NT) return;
    const int* row  = ghist + (size_t)wave * BLOCKS_P;
    int*       orow = goff  + (size_t)wave * BLOCKS_P;
    const int C = BLOCKS_P / 64;
    int v[C], pre[C];
    int lsum = 0;
#pragma unroll
    for (int i = 0; i < C; ++i) {
        v[i] = row[lane * C + i];
        pre[i] = lsum;
        lsum += v[i];
    }
    int incl = lsum;
#pragma unroll
    for (int d = 1; d < 64; d <<= 1) {
        int t = __shfl_up(incl, d, 64);
        if (lane >= d) incl += t;
    }
    const int excl = incl - lsum + csum[wave];
#pragma unroll
    for (int i = 0; i < C; ++i)
        orow[lane * C + i] = excl + pre[i];
}

// scatter: single 16B payload per point:
//   {w0|w1 packed u16, w2 u16, gbase, p}  (weights 16-bit fixed-point)
__global__ __launch_bounds__(256) void k_scatter(
    const float* __restrict__ points,
    const float* __restrict__ offset,
    const float* __restrict__ scaling,
    const int* __restrict__ goff,
    uint4* __restrict__ pay,
    int n, int ppb)
{
    __shared__ int cur[NT];
    const int b = blockIdx.x;
    for (int i = threadIdx.x; i < NT; i += 256)
        cur[i] = goff[(size_t)i * BLOCKS_P + b];
    __syncthreads();
    const int lo = b * ppb;
    const int hi = min(lo + ppb, n);
    for (int p = lo + threadIdx.x; p < hi; p += 256) {
        int l[3]; float wb[3];
        const int t = point_coords(points, offset, scaling, p, l, wb);
        const int slot = atomicAdd(&cur[t], 1);   // LDS atomic only
        const int gbase = (l[0] * RESO + l[1]) * RESO + l[2];
        const unsigned u0 = (unsigned)rintf(wb[0] * 65535.0f);
        const unsigned u1 = (unsigned)rintf(wb[1] * 65535.0f);
        const unsigned u2 = (unsigned)rintf(wb[2] * 65535.0f);
        uint4 v;
        v.x = u0 | (u1 << 16);
        v.y = u2;
        v.z = (unsigned)gbase;
        v.w = (unsigned)p;
        pay[slot] = v;
    }
}

// ---------------- main sampler: flat grid + per-XCD grid-stride ----------------

__global__ __launch_bounds__(256) void k_sample_sorted(
    const uint4* __restrict__ pay,
    const int*   __restrict__ csum,
    const float* __restrict__ data,
    const int*   __restrict__ links,
    const int*   __restrict__ flag,
    float*       __restrict__ out,
    int bpx)
{
    const int k = blockIdx.x & (NXCD - 1);   // XCD id (round-robin dispatch)
    const int j = blockIdx.x >> 3;
    const int lo = csum[k * TPX];
    const int hi = csum[(k + 1) * TPX];
    const int nwork = (hi - lo) * CHUNKS;
    const int stride = bpx * 256;
    const bool fast = (flag[0] != 0);        // uniform scalar branch
    const int dz = 1, dy = RESO, dx = RESO * RESO;
    const int offs[8] = {0, dz, dy, dy + dz, dx, dx + dz, dx + dy, dx + dy + dz};
    const float inv = 1.0f / 65535.0f;

    // grid-stride within the XCD range: covers any slab imbalance;
    // typical block runs exactly one iteration.
    for (int item = j * 256 + (int)threadIdx.x; item < nwork; item += stride) {
        const int slot = lo + item / CHUNKS;
        const int c    = item % CHUNKS;

        const uint4 pv = pay[slot];          // single 16B metadata load (broadcast)
        const float wx = (float)(pv.x & 0xFFFFu) * inv;
        const float wy = (float)(pv.x >> 16) * inv;
        const float wz = (float)(pv.y & 0xFFFFu) * inv;
        const int gbase = (int)pv.z;
        const int p     = (int)pv.w;

        float4 cv[8];
        if (fast) {
            const float* bA = data + (size_t)c * 4;
#pragma unroll
            for (int q = 0; q < 8; ++q)
                cv[q] = *reinterpret_cast<const float4*>(
                    bA + (size_t)(gbase + offs[q]) * DATA_DIM);
        } else {
            int lk[8];
#pragma unroll
            for (int q = 0; q < 8; ++q) lk[q] = links[gbase + offs[q]];
#pragma unroll
            for (int q = 0; q < 8; ++q)
                cv[q] = *reinterpret_cast<const float4*>(
                    data + (size_t)(lk[q] < 0 ? 0 : lk[q]) * DATA_DIM + (size_t)c * 4);
#pragma unroll
            for (int q = 0; q < 8; ++q)
                if (lk[q] < 0) cv[q] = make_float4(0.f, 0.f, 0.f, 0.f);
        }

        const float4 s = trilerp8(cv, wx, wy, wz);
        *reinterpret_cast<float4*>(out + (size_t)p * DATA_DIM + (size_t)c * 4) = s;
    }
}

// ---------------- fallback: direct order ----------------

__global__ __launch_bounds__(256) void k_sample_direct(
    const float* __restrict__ points,
    const float* __restrict__ data,
    const int*   __restrict__ links,
    const float* __restrict__ offset,
    const float* __restrict__ scaling,
    float*       __restrict__ out,
    int n_pts)
{
    const int tid = blockIdx.x * blockDim.x + threadIdx.x;
    const int total = n_pts * CHUNKS;
    if (tid >= total) return;
    const int p = tid / CHUNKS;
    const int c = tid - p * CHUNKS;

    int l[3]; float wb[3];
    (void)point_coords(points, offset, scaling, p, l, wb);
    const int gbase = (l[0] * RESO + l[1]) * RESO + l[2];

    const int dz = 1, dy = RESO, dx = RESO * RESO;
    int lk[8];
    lk[0] = links[gbase];
    lk[1] = links[gbase + dz];
    lk[2] = links[gbase + dy];
    lk[3] = links[gbase + dy + dz];
    lk[4] = links[gbase + dx];
    lk[5] = links[gbase + dx + dz];
    lk[6] = links[gbase + dx + dy];
    lk[7] = links[gbase + dx + dy + dz];

    float4 cv[8];
#pragma unroll
    for (int q = 0; q < 8; ++q) {
        const int idx = lk[q] < 0 ? 0 : lk[q];
        cv[q] = *reinterpret_cast<const float4*>(
            data + (size_t)idx * DATA_DIM + (size_t)c * 4);
    }
#pragma unroll
    for (int q = 0; q < 8; ++q)
        if (lk[q] < 0) cv[q] = make_float4(0.f, 0.f, 0.f, 0.f);

    const float4 s = trilerp8(cv, wb[0], wb[1], wb[2]);
    *reinterpret_cast<float4*>(out + (size_t)tid * 4) = s;
}

// ---------------- launch ----------------

extern "C" void kernel_launch(void* const* d_in, const int* in_sizes, int n_in,
                              void* d_out, int out_size, void* d_ws, size_t ws_size,
                              hipStream_t stream)
{
    const float* points  = (const float*)d_in[0];
    const float* data    = (const float*)d_in[1];
    const int*   links   = (const int*)d_in[2];
    const float* offset  = (const float*)d_in[3];
    const float* scaling = (const float*)d_in[4];
    float*       out     = (float*)d_out;

    const int n_pts = in_sizes[0] / 3;

    // ws layout: flag | ghist | goff | binsum | csum | pay
    size_t off = 0;
    auto alloc = [&](size_t bytes) {
        size_t a = off;
        off = (off + bytes + 255) & ~(size_t)255;
        return a;
    };
    const size_t o_flag   = alloc(4);
    const size_t o_ghist  = alloc((size_t)NT * BLOCKS_P * 4);
    const size_t o_goff   = alloc((size_t)NT * BLOCKS_P * 4);
    const size_t o_binsum = alloc((size_t)NT * 4);
    const size_t o_csum   = alloc((size_t)(NT + 1) * 4);
    const size_t o_pay    = alloc((size_t)n_pts * 16);
    const size_t need = off;

    if (ws_size >= need) {
        int*   flag   = (int*)((char*)d_ws + o_flag);
        int*   ghist  = (int*)((char*)d_ws + o_ghist);
        int*   goff   = (int*)((char*)d_ws + o_goff);
        int*   binsum = (int*)((char*)d_ws + o_binsum);
        int*   csum   = (int*)((char*)d_ws + o_csum);
        uint4* pay    = (uint4*)((char*)d_ws + o_pay);

        const int ppb = (n_pts + BLOCKS_P - 1) / BLOCKS_P;

        k_init_flag<<<1, 64, 0, stream>>>(flag);
        k_check_links<<<2048, 256, 0, stream>>>(links, flag);
        k_hist<<<BLOCKS_P, 256, 0, stream>>>(points, offset, scaling, ghist, n_pts, ppb);
        k_rowsum<<<(NT * 64 + 255) / 256, 256, 0, stream>>>(ghist, binsum);
        k_scan_bins<<<1, 1024, 0, stream>>>(binsum, csum);
        k_scan_blocks<<<(NT * 64 + 255) / 256, 256, 0, stream>>>(ghist, csum, goff);
        k_scatter<<<BLOCKS_P, 256, 0, stream>>>(points, offset, scaling, goff,
                                                pay, n_pts, ppb);

        const long long items_per_xcd =
            ((long long)n_pts * CHUNKS + NXCD - 1) / NXCD;
        const int bpx = (int)((items_per_xcd + 255) / 256);
        k_sample_sorted<<<bpx * NXCD, 256, 0, stream>>>(
            pay, csum, data, links, flag, out, bpx);
    } else {
        const int total = n_pts * CHUNKS;
        k_sample_direct<<<(total + 255) / 256, 256, 0, stream>>>(
            points, data, links, offset, scaling, out, n_pts);
    }
}